// Round 4
// baseline (481.441 us; speedup 1.0000x reference)
//
#include <hip/hip_runtime.h>
#include <hip/hip_cooperative_groups.h>
#include <stdint.h>

namespace cg = cooperative_groups;

#define NN 4096
#define DD 256
#define TH 0.04f

typedef __attribute__((ext_vector_type(4))) float f32x4;
typedef __attribute__((ext_vector_type(8))) short s16x8;

__device__ __forceinline__ unsigned short f2bf(float f) {
  union { float f; uint32_t u; } x; x.f = f;
  uint32_t u = x.u;
  return (unsigned short)((u + 0x7FFFu + ((u >> 16) & 1u)) >> 16);  // RNE
}
__device__ __forceinline__ float bf2f(unsigned short h) {
  union { uint32_t u; float f; } x; x.u = ((uint32_t)h) << 16;
  return x.f;
}

// ============ Phase A: scan A -> bitsT (transposed bit mask), row-degree
// (fully reduced in-block -> oi), per-block col partials. 256 blocks x 512.
__device__ __forceinline__ void phaseA(const float* __restrict__ A,
                                       unsigned short* __restrict__ bitsT,
                                       unsigned char* __restrict__ colpart,
                                       float* __restrict__ oi,
                                       uint32_t* smem_u32) {
  const int t = threadIdx.x, bb = blockIdx.x;
  const int h = t >> 8, tt = t & 255;          // half (8 rows each), col-owner
  const int w = t >> 6, lane = t & 63;
  const int u0 = bb * 16 + h * 8;
  const int wv = tt >> 2, q = tt & 3;          // 64-col word, 16-bit slot
  uint32_t cs[16];
#pragma unroll
  for (int k = 0; k < 16; ++k) cs[k] = 0;
  uint32_t rp[8];
#pragma unroll
  for (int rb = 0; rb < 2; ++rb) {
    f32x4 a[4][4];
#pragma unroll
    for (int r = 0; r < 4; ++r) {
      const f32x4* p = reinterpret_cast<const f32x4*>(A + (size_t)(u0 + rb * 4 + r) * NN + tt * 16);
#pragma unroll
      for (int c = 0; c < 4; ++c) a[r][c] = p[c];
    }
#pragma unroll
    for (int r = 0; r < 4; ++r) {
      uint32_t m = 0;
#pragma unroll
      for (int c = 0; c < 4; ++c)
#pragma unroll
        for (int j = 0; j < 4; ++j) m |= (a[r][c][j] >= TH ? 1u : 0u) << (c * 4 + j);
      const int u = u0 + rb * 4 + r;
      bitsT[(size_t)wv * 16384 + (size_t)u * 4 + q] = (unsigned short)m;
      rp[rb * 4 + r] = (uint32_t)__popc(m);
#pragma unroll
      for (int k = 0; k < 16; ++k) cs[k] += (m >> k) & 1u;
    }
  }
  uint4 pk;
  pk.x = cs[0]  | (cs[1]  << 8) | (cs[2]  << 16) | (cs[3]  << 24);
  pk.y = cs[4]  | (cs[5]  << 8) | (cs[6]  << 16) | (cs[7]  << 24);
  pk.z = cs[8]  | (cs[9]  << 8) | (cs[10] << 16) | (cs[11] << 24);
  pk.w = cs[12] | (cs[13] << 8) | (cs[14] << 16) | (cs[15] << 24);
  *reinterpret_cast<uint4*>(colpart + (size_t)(bb * 2 + h) * 4096 + tt * 16) = pk;
  // row-degree reduce: 8 shuffle chains per wave, then cross-wave via LDS
#pragma unroll
  for (int r = 0; r < 8; ++r) {
    uint32_t s = rp[r];
#pragma unroll
    for (int off = 32; off >= 1; off >>= 1) s += __shfl_down(s, off);
    if (lane == 0) smem_u32[w * 8 + r] = s;
  }
  __syncthreads();
  if (t < 16) {
    const int h2 = t >> 3, r2 = t & 7;
    uint32_t s = smem_u32[(h2 * 4 + 0) * 8 + r2] + smem_u32[(h2 * 4 + 1) * 8 + r2] +
                 smem_u32[(h2 * 4 + 2) * 8 + r2] + smem_u32[(h2 * 4 + 3) * 8 + r2];
    oi[bb * 16 + h2 * 8 + r2] = rsqrtf((float)(s + 1u));
  }
}

// ============ Phase B: col-degree reduce -> ii; W1/W2 transpose -> bf16.
__device__ __forceinline__ void phaseB(const unsigned char* __restrict__ colpart,
                                       const float* __restrict__ W1,
                                       const float* __restrict__ W2,
                                       float* __restrict__ ii,
                                       unsigned short* __restrict__ WTb,
                                       unsigned short* __restrict__ W2Tb) {
  const int t = threadIdx.x, bb = blockIdx.x;
  const int v = bb * 16 + (t >> 5);
  const int ch = t & 31;
  uint32_t s = 0;
#pragma unroll
  for (int j = 0; j < 16; ++j) s += colpart[(size_t)(ch * 16 + j) * 4096 + v];
#pragma unroll
  for (int off = 16; off >= 1; off >>= 1) s += __shfl_down(s, off, 32);
  if (ch == 0) ii[v] = rsqrtf((float)(s + 1u));
  if (bb < 32) {
    const float* W = (bb < 16) ? W1 : W2;
    unsigned short* Wo = (bb < 16) ? WTb : W2Tb;
    const int base = (bb & 15) * 4096 + t * 8;
#pragma unroll
    for (int e = 0; e < 8; ++e) {
      const int idx = base + e;
      const int d = idx >> 8, k = idx & 255;
      Wo[idx] = f2bf(W[k * 256 + d]);
    }
  }
}

// ============ Phase HW: hW = (H*oi[:,None])@W -> hWb [u][d], hWbT [d][u].
// Active blocks 0..63, 8 waves: wave w owns d-range w*32 (2 jn frags).
__device__ __forceinline__ void phase_hw(const float* __restrict__ H,
                                         const float* __restrict__ oi,
                                         const unsigned short* __restrict__ WT,
                                         unsigned short* __restrict__ hWb,
                                         unsigned short* __restrict__ hWbT,
                                         unsigned short* lt /* [64][260] */) {
  const int t = threadIdx.x;
  const int lane = t & 63, w = t >> 6, l15 = lane & 15, l4 = lane >> 4;
  const int u0 = blockIdx.x * 64;
  const f32x4 z = {0.f, 0.f, 0.f, 0.f};
  f32x4 acc[4][2];
#pragma unroll
  for (int i = 0; i < 4; ++i) { acc[i][0] = z; acc[i][1] = z; }
  float oiv[4];
#pragma unroll
  for (int i = 0; i < 4; ++i) oiv[i] = oi[u0 + i * 16 + l15];
#pragma unroll 1
  for (int ks = 0; ks < 8; ++ks) {
    const int k0 = ks * 32;
    s16x8 af[4];
#pragma unroll
    for (int i = 0; i < 4; ++i) {
      const f32x4* pa = reinterpret_cast<const f32x4*>(H + (size_t)(u0 + i * 16 + l15) * DD + k0 + l4 * 8);
      f32x4 a0 = pa[0], a1 = pa[1];
#pragma unroll
      for (int j = 0; j < 4; ++j) {
        af[i][j]     = (short)f2bf(a0[j] * oiv[i]);
        af[i][j + 4] = (short)f2bf(a1[j] * oiv[i]);
      }
    }
#pragma unroll
    for (int jn = 0; jn < 2; ++jn) {
      const int d = w * 32 + jn * 16 + l15;
      s16x8 bf = *reinterpret_cast<const s16x8*>(WT + (size_t)d * DD + k0 + l4 * 8);
#pragma unroll
      for (int i = 0; i < 4; ++i)
        acc[i][jn] = __builtin_amdgcn_mfma_f32_16x16x32_bf16(af[i], bf, acc[i][jn], 0, 0, 0);
    }
  }
#pragma unroll
  for (int i = 0; i < 4; ++i)
#pragma unroll
    for (int jn = 0; jn < 2; ++jn) {
      const int d = w * 32 + jn * 16 + l15;
#pragma unroll
      for (int r = 0; r < 4; ++r) {
        const int ul = i * 16 + l4 * 4 + r;      // C/D: row=(l>>4)*4+reg, col=l&15
        unsigned short hv = f2bf(acc[i][jn][r]);
        hWb[(size_t)(u0 + ul) * DD + d] = hv;
        lt[ul * 260 + d] = hv;
      }
    }
  __syncthreads();
  const int d = t & 255, chalf = t >> 8;
#pragma unroll
  for (int c2 = 0; c2 < 4; ++c2) {
    const int c = chalf * 4 + c2;
    uint4 val;
    val.x = (uint32_t)lt[(c*8+0)*260 + d] | ((uint32_t)lt[(c*8+1)*260 + d] << 16);
    val.y = (uint32_t)lt[(c*8+2)*260 + d] | ((uint32_t)lt[(c*8+3)*260 + d] << 16);
    val.z = (uint32_t)lt[(c*8+4)*260 + d] | ((uint32_t)lt[(c*8+5)*260 + d] << 16);
    val.w = (uint32_t)lt[(c*8+6)*260 + d] | ((uint32_t)lt[(c*8+7)*260 + d] << 16);
    *reinterpret_cast<uint4*>(hWbT + (size_t)d * NN + u0 + c * 8) = val;
  }
}

// ============ Phase SPMM: out[v][d] = relu((sum_u bit[v][u]*hW[u][d] + hW[v][d])*ii[v] + b[d])
// 256 blocks = 64 vt x 4 dq (XCD-swizzled: all dq of a vt on one XCD).
// 8 waves: wave w -> k-chunk (w>>1)*1024, d-sub (w&1)*32. LDS 4-way K-combine.
__device__ __forceinline__ void phase_spmm(const unsigned short* __restrict__ bitsT,
                                           const unsigned short* __restrict__ hWbT,
                                           const unsigned short* __restrict__ hWb,
                                           const float* __restrict__ ii,
                                           const float* __restrict__ bias,
                                           float* __restrict__ dst,
                                           float* lds /* [8][64][36] */) {
  const int t = threadIdx.x, bb = blockIdx.x;
  const int lane = t & 63, w = t >> 6, l15 = lane & 15, l4 = lane >> 4;
  const int xcd = bb & 7, idx = bb >> 3;
  const int vt = xcd * 8 + (idx >> 2), dq = idx & 3;
  const int V0 = vt * 64, D0 = dq * 64;
  const int kc = w >> 1, dsub = w & 1;
  const int kbase = kc * 1024;
  const uint64_t* bits64 = reinterpret_cast<const uint64_t*>(bitsT) + (size_t)vt * 4096;
  const unsigned short* Bbase = hWbT + (size_t)(D0 + dsub * 32 + l15) * NN + l4 * 8;

  const f32x4 z = {0.f, 0.f, 0.f, 0.f};
  f32x4 acc[4][2];
#pragma unroll
  for (int i = 0; i < 4; ++i) { acc[i][0] = z; acc[i][1] = z; }

  uint4 wa[4], wb[4];
  s16x8 ba[2], bbf[2];

  auto LOADW = [&](uint4* v4, s16x8* bfr, int k) {
    const uint4* p4 = reinterpret_cast<const uint4*>(bits64 + (size_t)k + l4 * 8);
#pragma unroll
    for (int j2 = 0; j2 < 4; ++j2) v4[j2] = p4[j2];
#pragma unroll
    for (int jj = 0; jj < 2; ++jj)
      bfr[jj] = *reinterpret_cast<const s16x8*>(Bbase + (size_t)jj * 16 * NN + k);
  };
  auto COMP = [&](const uint4* v4, const s16x8* bfr) {
    uint32_t wlo[8], whi[8];
#pragma unroll
    for (int j2 = 0; j2 < 4; ++j2) {
      wlo[2*j2]   = v4[j2].x; whi[2*j2]   = v4[j2].y;
      wlo[2*j2+1] = v4[j2].z; whi[2*j2+1] = v4[j2].w;
    }
#pragma unroll
    for (int i = 0; i < 4; ++i) {
      const uint32_t sh = ((i & 1) << 4) + l15;
      union { s16x8 v; uint32_t u[4]; } af;
#pragma unroll
      for (int q2 = 0; q2 < 4; ++q2) {
        uint32_t h0 = (i < 2) ? wlo[2*q2]   : whi[2*q2];
        uint32_t h1 = (i < 2) ? wlo[2*q2+1] : whi[2*q2+1];
        uint32_t p = ((h0 >> sh) & 1u) | (((h1 >> sh) & 1u) << 16);
        af.u[q2] = p * 0x3F80u;
      }
#pragma unroll
      for (int jj = 0; jj < 2; ++jj)
        acc[i][jj] = __builtin_amdgcn_mfma_f32_16x16x32_bf16(af.v, bfr[jj], acc[i][jj], 0, 0, 0);
    }
  };

  LOADW(wa, ba, kbase);
#pragma unroll 1
  for (int it = 0; it < 16; ++it) {
    LOADW(wb, bbf, kbase + it * 64 + 32);
    COMP(wa, ba);
    LOADW(wa, ba, kbase + ((it * 64 + 64) & 1023));   // wraps on last iter (unused)
    COMP(wb, bbf);
  }
  // write acc to LDS [w][64][36]
  float* ldw = lds + (size_t)w * 64 * 36;
#pragma unroll
  for (int i = 0; i < 4; ++i)
#pragma unroll
    for (int jj = 0; jj < 2; ++jj) {
      const int dl = jj * 16 + l15;
#pragma unroll
      for (int r = 0; r < 4; ++r) {
        const int vloc = i * 16 + l4 * 4 + r;
        ldw[vloc * 36 + dl] = acc[i][jj][r];
      }
    }
  __syncthreads();
  // combine 4 k-chunks + epilogue; thread owns (vloc = t>>3, d0 = (t&7)*8)
  const int vloc = t >> 3, d0 = (t & 7) * 8;
  const int vg = V0 + vloc;
  const float iv = ii[vg];
  f32x4 o0, o1;
#pragma unroll
  for (int dd = 0; dd < 8; ++dd) {
    const int d = d0 + dd;
    const int ds2 = d >> 5, dc = d & 31;
    float s = 0.f;
#pragma unroll
    for (int kc2 = 0; kc2 < 4; ++kc2)
      s += lds[(size_t)(kc2 * 2 + ds2) * 2304 + vloc * 36 + dc];
    s += bf2f(hWb[(size_t)vg * DD + D0 + d]);
    const float val = fmaxf(s * iv + bias[D0 + d], 0.f);
    if (dd < 4) o0[dd] = val; else o1[dd - 4] = val;
  }
  f32x4* po = reinterpret_cast<f32x4*>(dst + (size_t)vg * DD + D0 + d0);
  po[0] = o0; po[1] = o1;
}

// ============ single cooperative kernel ============
__global__ __launch_bounds__(512, 2) void k_gcn(const float* __restrict__ A,
                                                const float* __restrict__ feat,
                                                const float* __restrict__ W1,
                                                const float* __restrict__ b1,
                                                const float* __restrict__ W2,
                                                const float* __restrict__ b2,
                                                float* __restrict__ out,
                                                unsigned short* bitsT,
                                                unsigned char* colpart,
                                                unsigned short* hWbT,
                                                unsigned short* hWb,
                                                unsigned short* WTb,
                                                unsigned short* W2Tb,
                                                float* oi, float* ii) {
  __shared__ __align__(16) char smem[73728];
  cg::grid_group grid = cg::this_grid();

  phaseA(A, bitsT, colpart, oi, reinterpret_cast<uint32_t*>(smem));
  __threadfence();
  grid.sync();

  phaseB(colpart, W1, W2, ii, WTb, W2Tb);
  __threadfence();
  grid.sync();

  if (blockIdx.x < 64)
    phase_hw(feat, oi, WTb, hWb, hWbT, reinterpret_cast<unsigned short*>(smem));
  __threadfence();
  grid.sync();

  phase_spmm(bitsT, hWbT, hWb, ii, b1, out, reinterpret_cast<float*>(smem));
  __threadfence();
  grid.sync();

  if (blockIdx.x < 64)
    phase_hw(out, oi, W2Tb, hWb, hWbT, reinterpret_cast<unsigned short*>(smem));
  __threadfence();
  grid.sync();

  phase_spmm(bitsT, hWbT, hWb, ii, b2, out + (size_t)NN * DD, reinterpret_cast<float*>(smem));
}

extern "C" void kernel_launch(void* const* d_in, const int* in_sizes, int n_in,
                              void* d_out, int out_size, void* d_ws, size_t ws_size,
                              hipStream_t stream) {
  const float* A    = (const float*)d_in[0];
  const float* feat = (const float*)d_in[1];
  const float* W1   = (const float*)d_in[2];
  const float* b1   = (const float*)d_in[3];
  const float* W2   = (const float*)d_in[4];
  const float* b2   = (const float*)d_in[5];
  float* out = (float*)d_out;
  char* ws = (char*)d_ws;

  unsigned short* bitsT   = (unsigned short*)ws;                          // 2 MiB
  unsigned char*  colpart = (unsigned char*)(ws + (2u << 20));            // 2 MiB
  unsigned short* hWbT    = (unsigned short*)(ws + (4u << 20));           // 2 MiB
  unsigned short* hWb     = (unsigned short*)(ws + (6u << 20));           // 2 MiB
  unsigned short* WTb     = (unsigned short*)(ws + (8u << 20));           // 128 KiB
  unsigned short* W2Tb    = (unsigned short*)(ws + (8u << 20) + (1u << 17));
  float*          oi      = (float*)(ws + (8u << 20) + (2u << 17));
  float*          ii      = oi + NN;

  void* args[] = {&A, &feat, &W1, &b1, &W2, &b2, &out,
                  &bitsT, &colpart, &hWbT, &hWb, &WTb, &W2Tb, &oi, &ii};
  hipLaunchCooperativeKernel((void*)k_gcn, dim3(256), dim3(512), args, 0, stream);
}

// Round 5
// 133.649 us; speedup vs baseline: 3.6023x; 3.6023x over previous
//
#include <hip/hip_runtime.h>
#include <stdint.h>

#define NN 4096
#define DD 256
#define TH 0.04f

typedef __attribute__((ext_vector_type(4))) float f32x4;
typedef __attribute__((ext_vector_type(16))) float f32x16;
typedef __attribute__((ext_vector_type(8))) short s16x8;

__device__ __forceinline__ unsigned short f2bf(float f) {
  union { float f; uint32_t u; } x; x.f = f;
  uint32_t u = x.u;
  return (unsigned short)((u + 0x7FFFu + ((u >> 16) & 1u)) >> 16);  // RNE
}
__device__ __forceinline__ float bf2f(unsigned short h) {
  union { uint32_t u; float f; } x; x.u = ((uint32_t)h) << 16;
  return x.f;
}

// ---- pass over A: bitsT [256 wv][4096 u] (bit b of word = edge u->v=wv*16+b),
// col partials (u8), row degrees -> oi (in-block), W1/W2 transpose (b<32).
__global__ __launch_bounds__(256) void k_deg(const float* __restrict__ A,
                                             unsigned short* __restrict__ bitsT,
                                             unsigned char* __restrict__ colpart,
                                             float* __restrict__ oi,
                                             const float* __restrict__ W1,
                                             const float* __restrict__ W2,
                                             unsigned short* __restrict__ WTb,
                                             unsigned short* __restrict__ W2Tb) {
  __shared__ unsigned short lds16[256 * 8];   // [wv][u_loc]
  const int t = threadIdx.x, b = blockIdx.x;
  const int u0 = b * 8;
  uint32_t cs[16];
#pragma unroll
  for (int k = 0; k < 16; ++k) cs[k] = 0;
#pragma unroll
  for (int rb = 0; rb < 2; ++rb) {
    f32x4 a[4][4];
#pragma unroll
    for (int r = 0; r < 4; ++r) {
      const f32x4* p = reinterpret_cast<const f32x4*>(A + (size_t)(u0 + rb * 4 + r) * NN + t * 16);
#pragma unroll
      for (int c = 0; c < 4; ++c) a[r][c] = p[c];
    }
#pragma unroll
    for (int r = 0; r < 4; ++r) {
      uint32_t m = 0;
#pragma unroll
      for (int c = 0; c < 4; ++c)
#pragma unroll
        for (int j = 0; j < 4; ++j) m |= (a[r][c][j] >= TH ? 1u : 0u) << (c * 4 + j);
      lds16[t * 8 + rb * 4 + r] = (unsigned short)m;
#pragma unroll
      for (int k = 0; k < 16; ++k) cs[k] += (m >> k) & 1u;
    }
  }
  uint4 pk;
  pk.x = cs[0]  | (cs[1]  << 8) | (cs[2]  << 16) | (cs[3]  << 24);
  pk.y = cs[4]  | (cs[5]  << 8) | (cs[6]  << 16) | (cs[7]  << 24);
  pk.z = cs[8]  | (cs[9]  << 8) | (cs[10] << 16) | (cs[11] << 24);
  pk.w = cs[12] | (cs[13] << 8) | (cs[14] << 16) | (cs[15] << 24);
  *reinterpret_cast<uint4*>(colpart + (size_t)b * 4096 + t * 16) = pk;
  __syncthreads();
  // bits writeout: thread t owns window t, 8 u16 = 16B at bitsT[t*4096+u0]
  uint4 wv4 = *reinterpret_cast<const uint4*>(&lds16[t * 8]);
  *reinterpret_cast<uint4*>(bitsT + (size_t)t * 4096 + u0) = wv4;
  // row degrees: 8 rows, 8 partials each
  if (t < 64) {
    const int r = t >> 3, part = t & 7;
    uint32_t s = 0;
#pragma unroll
    for (int wv = part * 32; wv < part * 32 + 32; ++wv)
      s += (uint32_t)__popc((uint32_t)lds16[wv * 8 + r]);
    s += __shfl_down(s, 4, 8);
    s += __shfl_down(s, 2, 8);
    s += __shfl_down(s, 1, 8);
    if (part == 0) oi[u0 + r] = rsqrtf((float)(s + 1u));
  }
  // W transpose -> bf16 (blocks 0..31)
  if (b < 32) {
    const float* W = (b < 16) ? W1 : W2;
    unsigned short* Wo = (b < 16) ? WTb : W2Tb;
    const int base = (b & 15) * 4096 + t * 16;
#pragma unroll
    for (int e = 0; e < 16; ++e) {
      const int idx = base + e;
      const int d = idx >> 8, k = idx & 255;
      Wo[idx] = f2bf(W[k * 256 + d]);
    }
  }
}

// ---- hW = (H * oi[:,None]) @ W -> hWb [u][d], hWbT [d][u]; + ii reduce (doii)
__global__ __launch_bounds__(256) void k_hw(const float* __restrict__ H,
                                            const float* __restrict__ oi,
                                            const unsigned short* __restrict__ WT,
                                            unsigned short* __restrict__ hWb,
                                            unsigned short* __restrict__ hWbT,
                                            const unsigned char* __restrict__ colpart,
                                            float* __restrict__ ii,
                                            int doii) {
  __shared__ unsigned short lt[64 * 260];
  uint32_t* ldsw = reinterpret_cast<uint32_t*>(lt);
  const int t = threadIdx.x;
  if (doii) {
    const int v0 = blockIdx.x * 64;
    const int grp = t >> 4, vg = t & 15;   // 16 row-groups x 16 v-quads
    uint32_t alo = 0, ahi = 0;
#pragma unroll 4
    for (int r = grp * 32; r < grp * 32 + 32; ++r) {
      uint32_t x = *reinterpret_cast<const uint32_t*>(colpart + (size_t)r * 4096 + v0 + vg * 4);
      alo += x & 0x00FF00FFu;
      ahi += (x >> 8) & 0x00FF00FFu;
    }
    ldsw[t * 2] = alo;
    ldsw[t * 2 + 1] = ahi;
    __syncthreads();
    if (t < 64) {
      const int vg2 = t >> 2, pos = t & 3;
      const int reg = pos & 1, half = pos >> 1;
      uint32_t s = 0;
#pragma unroll
      for (int g = 0; g < 16; ++g)
        s += (ldsw[(g * 16 + vg2) * 2 + reg] >> (half * 16)) & 0xFFFFu;
      ii[v0 + t] = rsqrtf((float)(s + 1u));
    }
  }
  __syncthreads();

  const int lane = t & 63, w = t >> 6, l15 = lane & 15, l4 = lane >> 4;
  const int u0 = blockIdx.x * 64;
  const f32x4 z = {0.f, 0.f, 0.f, 0.f};
  f32x4 acc[4][4];
#pragma unroll
  for (int i = 0; i < 4; ++i)
#pragma unroll
    for (int j = 0; j < 4; ++j) acc[i][j] = z;
  float oiv[4];
#pragma unroll
  for (int i = 0; i < 4; ++i) oiv[i] = oi[u0 + i * 16 + l15];

#pragma unroll 1
  for (int ks = 0; ks < 8; ++ks) {
    const int k0 = ks * 32;
    s16x8 af[4];
#pragma unroll
    for (int i = 0; i < 4; ++i) {
      const f32x4* pa = reinterpret_cast<const f32x4*>(H + (size_t)(u0 + i * 16 + l15) * DD + k0 + l4 * 8);
      f32x4 a0 = pa[0], a1 = pa[1];
#pragma unroll
      for (int j = 0; j < 4; ++j) {
        af[i][j]     = (short)f2bf(a0[j] * oiv[i]);
        af[i][j + 4] = (short)f2bf(a1[j] * oiv[i]);
      }
    }
#pragma unroll
    for (int jn = 0; jn < 4; ++jn) {
      const int d = w * 64 + jn * 16 + l15;
      s16x8 bf = *reinterpret_cast<const s16x8*>(WT + (size_t)d * DD + k0 + l4 * 8);
#pragma unroll
      for (int i = 0; i < 4; ++i)
        acc[i][jn] = __builtin_amdgcn_mfma_f32_16x16x32_bf16(af[i], bf, acc[i][jn], 0, 0, 0);
    }
  }
#pragma unroll
  for (int i = 0; i < 4; ++i)
#pragma unroll
    for (int jn = 0; jn < 4; ++jn) {
      const int d = w * 64 + jn * 16 + l15;
#pragma unroll
      for (int r = 0; r < 4; ++r) {
        const int ul = i * 16 + l4 * 4 + r;      // C/D: row=(l>>4)*4+reg, col=l&15
        unsigned short hv = f2bf(acc[i][jn][r]);
        hWb[(size_t)(u0 + ul) * DD + d] = hv;
        lt[ul * 260 + d] = hv;
      }
    }
  __syncthreads();
#pragma unroll
  for (int c = 0; c < 8; ++c) {                  // thread t owns hWbT row d=t
    uint4 val;
    val.x = (uint32_t)lt[(c*8+0)*260 + t] | ((uint32_t)lt[(c*8+1)*260 + t] << 16);
    val.y = (uint32_t)lt[(c*8+2)*260 + t] | ((uint32_t)lt[(c*8+3)*260 + t] << 16);
    val.z = (uint32_t)lt[(c*8+4)*260 + t] | ((uint32_t)lt[(c*8+5)*260 + t] << 16);
    val.w = (uint32_t)lt[(c*8+6)*260 + t] | ((uint32_t)lt[(c*8+7)*260 + t] << 16);
    *reinterpret_cast<uint4*>(hWbT + (size_t)t * NN + u0 + c * 8) = val;
  }
}

// ---- fused SpMM: out[v][d] = relu((sum_u bit[u][v]*hW[u][d] + hW[v][d])*ii[v] + b[d])
// Grid 256 = 64 vt x 4 dq (XCD-swizzled). Block 512 = 8 waves = 2 mi x 4 kc.
// Wave: m32(v) x d64 (2 n-tiles) x K1024, 32x32x16 MFMA, packed bit-expansion.
__global__ __launch_bounds__(512, 4) void k_spmm(const unsigned short* __restrict__ bitsT,
                                                 const unsigned short* __restrict__ hWbT,
                                                 const unsigned short* __restrict__ hWb,
                                                 const float* __restrict__ ii,
                                                 const float* __restrict__ bias,
                                                 float* __restrict__ dst) {
  __shared__ float lds[4 * 64 * 68];             // [kc][64v][68(d pad)]
  const int t = threadIdx.x, bb = blockIdx.x;
  const int lane = t & 63, w = t >> 6;
  const int mi = w & 1, kc = w >> 1;
  const int xcd = bb & 7, jj = bb >> 3;
  const int vt = xcd * 8 + (jj >> 2), dq = jj & 3;
  const int V0 = vt * 64, D0 = dq * 64;
  const int l31 = lane & 31, l5 = lane >> 5;
  const uint32_t sh = lane & 15;
  const int wvl = vt * 4 + mi * 2 + ((lane >> 4) & 1);
  const unsigned short* Ab = bitsT + (size_t)wvl * 4096 + l5 * 8;
  const unsigned short* B0 = hWbT + (size_t)(D0 + l31) * 4096 + l5 * 8;
  const unsigned short* B1 = hWbT + (size_t)(D0 + 32 + l31) * 4096 + l5 * 8;
  const int kb = kc * 1024;

  f32x16 acc0, acc1;
#pragma unroll
  for (int q = 0; q < 16; ++q) { acc0[q] = 0.f; acc1[q] = 0.f; }

  uint4 ha = *reinterpret_cast<const uint4*>(Ab + kb);
  s16x8 b0a = *reinterpret_cast<const s16x8*>(B0 + kb);
  s16x8 b1a = *reinterpret_cast<const s16x8*>(B1 + kb);

#pragma unroll 1
  for (int s = 0; s < 64; ++s) {
    const int kn = kb + ((s + 1) & 63) * 16;     // wraps on last iter (unused)
    uint4 hb = *reinterpret_cast<const uint4*>(Ab + kn);
    s16x8 b0b = *reinterpret_cast<const s16x8*>(B0 + kn);
    s16x8 b1b = *reinterpret_cast<const s16x8*>(B1 + kn);
    union { s16x8 v; uint32_t u[4]; } af;
    af.u[0] = ((ha.x >> sh) & 0x10001u) * 0x3F80u;
    af.u[1] = ((ha.y >> sh) & 0x10001u) * 0x3F80u;
    af.u[2] = ((ha.z >> sh) & 0x10001u) * 0x3F80u;
    af.u[3] = ((ha.w >> sh) & 0x10001u) * 0x3F80u;
    acc0 = __builtin_amdgcn_mfma_f32_32x32x16_bf16(af.v, b0a, acc0, 0, 0, 0);
    acc1 = __builtin_amdgcn_mfma_f32_32x32x16_bf16(af.v, b1a, acc1, 0, 0, 0);
    ha = hb; b0a = b0b; b1a = b1b;
  }

  // acc -> LDS buf[kc]; C/D 32x32: col=lane&31, row=(reg&3)+8*(reg>>2)+4*(lane>>5)
  float* buf = lds + (size_t)kc * (64 * 68);
#pragma unroll
  for (int reg = 0; reg < 16; ++reg) {
    const int row = (reg & 3) + 8 * (reg >> 2) + 4 * l5;
    buf[(mi * 32 + row) * 68 + l31] = acc0[reg];
    buf[(mi * 32 + row) * 68 + 32 + l31] = acc1[reg];
  }
  __syncthreads();

  // epilogue: thread owns (vloc = t>>3, 8 d at (t&7)*8)
  const int vloc = t >> 3, d8 = (t & 7) * 8;
  const int v = V0 + vloc;
  const float* base = lds + vloc * 68 + d8;
  f32x4 s0 = *reinterpret_cast<const f32x4*>(base);
  f32x4 s1 = *reinterpret_cast<const f32x4*>(base + 4);
#pragma unroll
  for (int q = 1; q < 4; ++q) {
    s0 += *reinterpret_cast<const f32x4*>(base + q * (64 * 68));
    s1 += *reinterpret_cast<const f32x4*>(base + q * (64 * 68) + 4);
  }
  union { s16x8 v; unsigned short us[8]; } self;
  self.v = *reinterpret_cast<const s16x8*>(hWb + (size_t)v * DD + D0 + d8);
  const float iv = ii[v];
  const f32x4 bi0 = *reinterpret_cast<const f32x4*>(bias + D0 + d8);
  const f32x4 bi1 = *reinterpret_cast<const f32x4*>(bias + D0 + d8 + 4);
  f32x4 o0, o1;
#pragma unroll
  for (int e = 0; e < 4; ++e) {
    o0[e] = fmaxf((s0[e] + bf2f(self.us[e])) * iv + bi0[e], 0.f);
    o1[e] = fmaxf((s1[e] + bf2f(self.us[e + 4])) * iv + bi1[e], 0.f);
  }
  f32x4* po = reinterpret_cast<f32x4*>(dst + (size_t)v * DD + D0 + d8);
  po[0] = o0; po[1] = o1;
}

extern "C" void kernel_launch(void* const* d_in, const int* in_sizes, int n_in,
                              void* d_out, int out_size, void* d_ws, size_t ws_size,
                              hipStream_t stream) {
  const float* A    = (const float*)d_in[0];
  const float* feat = (const float*)d_in[1];
  const float* W1   = (const float*)d_in[2];
  const float* b1   = (const float*)d_in[3];
  const float* W2   = (const float*)d_in[4];
  const float* b2   = (const float*)d_in[5];
  float* out = (float*)d_out;
  char* ws = (char*)d_ws;

  unsigned short* bitsT   = (unsigned short*)ws;                          // 2 MiB
  unsigned char*  colpart = (unsigned char*)(ws + (2u << 20));            // 2 MiB
  unsigned short* hWbT    = (unsigned short*)(ws + (4u << 20));           // 2 MiB
  unsigned short* hWb     = (unsigned short*)(ws + (6u << 20));           // 2 MiB
  unsigned short* WTb     = (unsigned short*)(ws + (8u << 20));           // 128 KiB
  unsigned short* W2Tb    = (unsigned short*)(ws + (8u << 20) + (1u << 17));
  float*          oi      = (float*)(ws + (8u << 20) + (2u << 17));       // 16 KiB
  float*          ii      = oi + NN;

  k_deg<<<512, 256, 0, stream>>>(A, bitsT, colpart, oi, W1, W2, WTb, W2Tb);

  // layer 1 (k_hw also reduces colpart -> ii)
  k_hw<<<64, 256, 0, stream>>>(feat, oi, WTb, hWb, hWbT, colpart, ii, 1);
  k_spmm<<<256, 512, 0, stream>>>(bitsT, hWbT, hWb, ii, b1, out);

  // layer 2
  k_hw<<<64, 256, 0, stream>>>(out, oi, W2Tb, hWb, hWbT, colpart, ii, 0);
  k_spmm<<<256, 512, 0, stream>>>(bitsT, hWbT, hWb, ii, b2, out + (size_t)NN * DD);
}

// Round 6
// 74.997 us; speedup vs baseline: 6.4195x; 1.7821x over previous
//
#include <hip/hip_runtime.h>
#include <stdint.h>

#define NN 4096
#define DD 256
#define TH 0.04f

typedef __attribute__((ext_vector_type(4))) float f32x4;
typedef __attribute__((ext_vector_type(16))) float f32x16;
typedef __attribute__((ext_vector_type(8))) short s16x8;

__device__ __forceinline__ unsigned short f2bf(float f) {
  union { float f; uint32_t u; } x; x.f = f;
  uint32_t u = x.u;
  return (unsigned short)((u + 0x7FFFu + ((u >> 16) & 1u)) >> 16);  // RNE
}
__device__ __forceinline__ float bf2f(unsigned short h) {
  union { uint32_t u; float f; } x; x.u = ((uint32_t)h) << 16;
  return x.f;
}

// ---- pass over A: bitsT [256 wv][4096 u], col partials, row degrees -> oi,
// ---- W1/W2 -> bf16 fragment panels (16x16x32 B-frag order) on blocks 0..31.
__global__ __launch_bounds__(256) void k_deg(const float* __restrict__ A,
                                             unsigned short* __restrict__ bitsT,
                                             unsigned char* __restrict__ colpart,
                                             float* __restrict__ oi,
                                             const float* __restrict__ W1,
                                             const float* __restrict__ W2,
                                             unsigned short* __restrict__ WTbP,
                                             unsigned short* __restrict__ W2TbP) {
  __shared__ unsigned short lds16[256 * 8];   // [wv][u_loc]
  const int t = threadIdx.x, b = blockIdx.x;
  const int u0 = b * 8;
  uint32_t cs[16];
#pragma unroll
  for (int k = 0; k < 16; ++k) cs[k] = 0;
#pragma unroll
  for (int rb = 0; rb < 2; ++rb) {
    f32x4 a[4][4];
#pragma unroll
    for (int r = 0; r < 4; ++r) {
      const f32x4* p = reinterpret_cast<const f32x4*>(A + (size_t)(u0 + rb * 4 + r) * NN + t * 16);
#pragma unroll
      for (int c = 0; c < 4; ++c) a[r][c] = p[c];
    }
#pragma unroll
    for (int r = 0; r < 4; ++r) {
      uint32_t m = 0;
#pragma unroll
      for (int c = 0; c < 4; ++c)
#pragma unroll
        for (int j = 0; j < 4; ++j) m |= (a[r][c][j] >= TH ? 1u : 0u) << (c * 4 + j);
      lds16[t * 8 + rb * 4 + r] = (unsigned short)m;
#pragma unroll
      for (int k = 0; k < 16; ++k) cs[k] += (m >> k) & 1u;
    }
  }
  uint4 pk;
  pk.x = cs[0]  | (cs[1]  << 8) | (cs[2]  << 16) | (cs[3]  << 24);
  pk.y = cs[4]  | (cs[5]  << 8) | (cs[6]  << 16) | (cs[7]  << 24);
  pk.z = cs[8]  | (cs[9]  << 8) | (cs[10] << 16) | (cs[11] << 24);
  pk.w = cs[12] | (cs[13] << 8) | (cs[14] << 16) | (cs[15] << 24);
  *reinterpret_cast<uint4*>(colpart + (size_t)b * 4096 + t * 16) = pk;
  __syncthreads();
  // bits writeout: thread t owns window t, 8 u16 = 16B at bitsT[t*4096+u0]
  uint4 wv4 = *reinterpret_cast<const uint4*>(&lds16[t * 8]);
  *reinterpret_cast<uint4*>(bitsT + (size_t)t * 4096 + u0) = wv4;
  // row degrees
  if (t < 64) {
    const int r = t >> 3, part = t & 7;
    uint32_t s = 0;
#pragma unroll
    for (int wv = part * 32; wv < part * 32 + 32; ++wv)
      s += (uint32_t)__popc((uint32_t)lds16[wv * 8 + r]);
    s += __shfl_down(s, 4, 8);
    s += __shfl_down(s, 2, 8);
    s += __shfl_down(s, 1, 8);
    if (part == 0) oi[u0 + r] = rsqrtf((float)(s + 1u));
  }
  // W -> bf16 fragment panels (blocks 0..31): frag (dt16,ks32): pos lane*8+j =
  // W[k = ks*32 + (lane>>4)*8 + j][d = dt*16 + (lane&15)]
  if (b < 32) {
    const float* W = (b < 16) ? W1 : W2;
    unsigned short* Wo = (b < 16) ? WTbP : W2TbP;
    const int base = (b & 15) * 4096 + t * 16;
#pragma unroll
    for (int e = 0; e < 16; ++e) {
      const int idx = base + e;
      const int frag = idx >> 9, pos = idx & 511;
      const int lc = pos >> 3, j = pos & 7;
      const int dt = frag >> 3, ks = frag & 7;
      const int k = ks * 32 + (lc >> 4) * 8 + j;
      const int d = dt * 16 + (lc & 15);
      Wo[idx] = f2bf(W[k * 256 + d]);
    }
  }
}

// ---- hW = (H*oi)@W -> hWb [u][d] (self term) + hWbP (32x32x16 B-frag panels)
// Grid 256 (u16/block), block 256 = 4 waves (wave w -> d w*64..+63).
__global__ __launch_bounds__(256) void k_hw(const float* __restrict__ H,
                                            const float* __restrict__ oi,
                                            const unsigned short* __restrict__ WTbP,
                                            unsigned short* __restrict__ hWb,
                                            unsigned short* __restrict__ hWbP,
                                            const unsigned char* __restrict__ colpart,
                                            float* __restrict__ ii,
                                            int doii) {
  __shared__ unsigned short hs[16 * 264];   // staged (H*oi) bf16 tile
  __shared__ unsigned short lt[16 * 260];   // output tile for panel permute
  const int t = threadIdx.x;
  const int u0 = blockIdx.x * 16;
  if (doii) {   // col-degree reduce for 16 v's (pure shuffle)
    const int v0 = blockIdx.x * 16;
    const int vI = t >> 4, g = t & 15;
    uint32_t s = 0;
#pragma unroll 8
    for (int r = g * 32; r < g * 32 + 32; ++r)
      s += colpart[(size_t)r * 4096 + v0 + vI];
    s += __shfl_down(s, 8, 16);
    s += __shfl_down(s, 4, 16);
    s += __shfl_down(s, 2, 16);
    s += __shfl_down(s, 1, 16);
    if (g == 0) ii[v0 + vI] = rsqrtf((float)(s + 1u));
  }
  // stage hs[row][k] = bf16(H[u0+row][k] * oi[u0+row]), coalesced
#pragma unroll
  for (int rep = 0; rep < 4; ++rep) {
    const int flat = rep * 256 + t;
    const int row = flat >> 6, c4 = flat & 63;
    f32x4 v = *reinterpret_cast<const f32x4*>(H + (size_t)(u0 + row) * DD + c4 * 4);
    const float sc = oi[u0 + row];
    uint2 pw;
    pw.x = (uint32_t)f2bf(v[0] * sc) | ((uint32_t)f2bf(v[1] * sc) << 16);
    pw.y = (uint32_t)f2bf(v[2] * sc) | ((uint32_t)f2bf(v[3] * sc) << 16);
    *reinterpret_cast<uint2*>(&hs[row * 264 + c4 * 4]) = pw;
  }
  __syncthreads();

  const int lane = t & 63, w = t >> 6, l15 = lane & 15, l4 = lane >> 4;
  const f32x4 z = {0.f, 0.f, 0.f, 0.f};
  f32x4 acc[4];
#pragma unroll
  for (int jn = 0; jn < 4; ++jn) acc[jn] = z;

#pragma unroll
  for (int ks = 0; ks < 8; ++ks) {
    s16x8 af = *reinterpret_cast<const s16x8*>(&hs[l15 * 264 + ks * 32 + l4 * 8]);
#pragma unroll
    for (int jn = 0; jn < 4; ++jn) {
      const int dt = w * 4 + jn;
      s16x8 bf = *reinterpret_cast<const s16x8*>(WTbP + ((size_t)dt * 8 + ks) * 512 + lane * 8);
      acc[jn] = __builtin_amdgcn_mfma_f32_16x16x32_bf16(af, bf, acc[jn], 0, 0, 0);
    }
  }
  // C/D 16x16: row(u_loc) = l4*4+r, col(d) = l15
#pragma unroll
  for (int jn = 0; jn < 4; ++jn) {
    const int d = w * 64 + jn * 16 + l15;
#pragma unroll
    for (int r = 0; r < 4; ++r) {
      const int ul = l4 * 4 + r;
      unsigned short hv = f2bf(acc[jn][r]);
      hWb[(size_t)(u0 + ul) * DD + d] = hv;
      lt[ul * 260 + d] = hv;
    }
  }
  __syncthreads();
  // panel write: frag (dt32, s_glob=u0/16): pos lane*8+j =
  //   hW[u = s_glob*16 + (lane>>5)*8 + j][d = dt*32 + (lane&31)]
  const int sg = u0 >> 4;
#pragma unroll
  for (int cc = 0; cc < 2; ++cc) {
    const int c = t * 2 + cc;
    const int dt = c >> 6, lc = c & 63;
    const int ub = (lc >> 5) * 8;
    const int d = dt * 32 + (lc & 31);
    uint4 val;
    val.x = (uint32_t)lt[(ub + 0) * 260 + d] | ((uint32_t)lt[(ub + 1) * 260 + d] << 16);
    val.y = (uint32_t)lt[(ub + 2) * 260 + d] | ((uint32_t)lt[(ub + 3) * 260 + d] << 16);
    val.z = (uint32_t)lt[(ub + 4) * 260 + d] | ((uint32_t)lt[(ub + 5) * 260 + d] << 16);
    val.w = (uint32_t)lt[(ub + 6) * 260 + d] | ((uint32_t)lt[(ub + 7) * 260 + d] << 16);
    *reinterpret_cast<uint4*>(hWbP + ((size_t)dt * 256 + sg) * 512 + lc * 8) = val;
  }
}

// ---- fused SpMM: out[v][d] = relu((sum_u bit[u][v]*hW[u][d] + hW[v][d])*ii[v] + b[d])
// Grid 256 = 64 vt x 4 dq (XCD-swizzled). Block 512 = 8 waves = 2 mi x 4 kc.
// Coalesced panel B loads, depth-2 register prefetch, LDS 4-way K-combine.
__global__ __launch_bounds__(512, 2) void k_spmm(const unsigned short* __restrict__ bitsT,
                                                 const unsigned short* __restrict__ hWbP,
                                                 const unsigned short* __restrict__ hWb,
                                                 const float* __restrict__ ii,
                                                 const float* __restrict__ bias,
                                                 float* __restrict__ dst) {
  __shared__ float lds[4 * 64 * 68];             // [kc][64v][68(d pad)]
  const int t = threadIdx.x, bb = blockIdx.x;
  const int lane = t & 63, w = t >> 6;
  const int mi = w & 1, kc = w >> 1;
  const int xcd = bb & 7, jj = bb >> 3;
  const int vt = xcd * 8 + (jj >> 2), dq = jj & 3;
  const int V0 = vt * 64, D0 = dq * 64;
  const int l31 = lane & 31, l5 = lane >> 5;
  const uint32_t sh = lane & 15;
  const int wvl = vt * 4 + mi * 2 + ((lane >> 4) & 1);
  const unsigned short* Ab = bitsT + (size_t)wvl * 4096 + l5 * 8 + kc * 1024;
  const unsigned short* Bp0 = hWbP + ((size_t)(dq * 2 + 0) * 256 + kc * 64) * 512 + lane * 8;
  const unsigned short* Bp1 = hWbP + ((size_t)(dq * 2 + 1) * 256 + kc * 64) * 512 + lane * 8;

  f32x16 acc0, acc1;
#pragma unroll
  for (int q = 0; q < 16; ++q) { acc0[q] = 0.f; acc1[q] = 0.f; }

  uint4 h0 = *reinterpret_cast<const uint4*>(Ab);
  s16x8 p00 = *reinterpret_cast<const s16x8*>(Bp0);
  s16x8 p10 = *reinterpret_cast<const s16x8*>(Bp1);
  uint4 h1 = *reinterpret_cast<const uint4*>(Ab + 16);
  s16x8 p01 = *reinterpret_cast<const s16x8*>(Bp0 + 512);
  s16x8 p11 = *reinterpret_cast<const s16x8*>(Bp1 + 512);

#pragma unroll 1
  for (int it = 0; it < 32; ++it) {
    union { s16x8 v; uint32_t u[4]; } af0;
    af0.u[0] = ((h0.x >> sh) & 0x10001u) * 0x3F80u;
    af0.u[1] = ((h0.y >> sh) & 0x10001u) * 0x3F80u;
    af0.u[2] = ((h0.z >> sh) & 0x10001u) * 0x3F80u;
    af0.u[3] = ((h0.w >> sh) & 0x10001u) * 0x3F80u;
    acc0 = __builtin_amdgcn_mfma_f32_32x32x16_bf16(af0.v, p00, acc0, 0, 0, 0);
    acc1 = __builtin_amdgcn_mfma_f32_32x32x16_bf16(af0.v, p10, acc1, 0, 0, 0);
    const int s0 = (it * 2 + 2) & 63;                // wraps on last iter (unused)
    h0 = *reinterpret_cast<const uint4*>(Ab + s0 * 16);
    p00 = *reinterpret_cast<const s16x8*>(Bp0 + s0 * 512);
    p10 = *reinterpret_cast<const s16x8*>(Bp1 + s0 * 512);
    union { s16x8 v; uint32_t u[4]; } af1;
    af1.u[0] = ((h1.x >> sh) & 0x10001u) * 0x3F80u;
    af1.u[1] = ((h1.y >> sh) & 0x10001u) * 0x3F80u;
    af1.u[2] = ((h1.z >> sh) & 0x10001u) * 0x3F80u;
    af1.u[3] = ((h1.w >> sh) & 0x10001u) * 0x3F80u;
    acc0 = __builtin_amdgcn_mfma_f32_32x32x16_bf16(af1.v, p01, acc0, 0, 0, 0);
    acc1 = __builtin_amdgcn_mfma_f32_32x32x16_bf16(af1.v, p11, acc1, 0, 0, 0);
    const int s1 = (it * 2 + 3) & 63;
    h1 = *reinterpret_cast<const uint4*>(Ab + s1 * 16);
    p01 = *reinterpret_cast<const s16x8*>(Bp0 + s1 * 512);
    p11 = *reinterpret_cast<const s16x8*>(Bp1 + s1 * 512);
  }

  // acc -> LDS buf[kc]; C/D 32x32: col=lane&31, row=(reg&3)+8*(reg>>2)+4*(lane>>5)
  float* buf = lds + (size_t)kc * (64 * 68);
#pragma unroll
  for (int reg = 0; reg < 16; ++reg) {
    const int row = (reg & 3) + 8 * (reg >> 2) + 4 * l5;
    buf[(mi * 32 + row) * 68 + l31] = acc0[reg];
    buf[(mi * 32 + row) * 68 + 32 + l31] = acc1[reg];
  }
  __syncthreads();

  // epilogue: thread owns (vloc = t>>3, 8 d at (t&7)*8)
  const int vloc = t >> 3, d8 = (t & 7) * 8;
  const int v = V0 + vloc;
  const float* base = lds + vloc * 68 + d8;
  f32x4 s0v = *reinterpret_cast<const f32x4*>(base);
  f32x4 s1v = *reinterpret_cast<const f32x4*>(base + 4);
#pragma unroll
  for (int q = 1; q < 4; ++q) {
    s0v += *reinterpret_cast<const f32x4*>(base + q * (64 * 68));
    s1v += *reinterpret_cast<const f32x4*>(base + q * (64 * 68) + 4);
  }
  union { s16x8 v; unsigned short us[8]; } self;
  self.v = *reinterpret_cast<const s16x8*>(hWb + (size_t)v * DD + D0 + d8);
  const float iv = ii[v];
  const f32x4 bi0 = *reinterpret_cast<const f32x4*>(bias + D0 + d8);
  const f32x4 bi1 = *reinterpret_cast<const f32x4*>(bias + D0 + d8 + 4);
  f32x4 o0, o1;
#pragma unroll
  for (int e = 0; e < 4; ++e) {
    o0[e] = fmaxf((s0v[e] + bf2f(self.us[e])) * iv + bi0[e], 0.f);
    o1[e] = fmaxf((s1v[e] + bf2f(self.us[e + 4])) * iv + bi1[e], 0.f);
  }
  f32x4* po = reinterpret_cast<f32x4*>(dst + (size_t)v * DD + D0 + d8);
  po[0] = o0; po[1] = o1;
}

extern "C" void kernel_launch(void* const* d_in, const int* in_sizes, int n_in,
                              void* d_out, int out_size, void* d_ws, size_t ws_size,
                              hipStream_t stream) {
  const float* A    = (const float*)d_in[0];
  const float* feat = (const float*)d_in[1];
  const float* W1   = (const float*)d_in[2];
  const float* b1   = (const float*)d_in[3];
  const float* W2   = (const float*)d_in[4];
  const float* b2   = (const float*)d_in[5];
  float* out = (float*)d_out;
  char* ws = (char*)d_ws;

  unsigned short* bitsT   = (unsigned short*)ws;                          // 2 MiB
  unsigned char*  colpart = (unsigned char*)(ws + (2u << 20));            // 2 MiB
  unsigned short* hWbP    = (unsigned short*)(ws + (4u << 20));           // 2 MiB
  unsigned short* hWb     = (unsigned short*)(ws + (6u << 20));           // 2 MiB
  unsigned short* WTbP    = (unsigned short*)(ws + (8u << 20));           // 128 KiB
  unsigned short* W2TbP   = (unsigned short*)(ws + (8u << 20) + (1u << 17));
  float*          oi      = (float*)(ws + (8u << 20) + (2u << 17));       // 16 KiB
  float*          ii      = oi + NN;

  k_deg<<<512, 256, 0, stream>>>(A, bitsT, colpart, oi, W1, W2, WTbP, W2TbP);

  // layer 1 (k_hw also reduces colpart -> ii)
  k_hw<<<256, 256, 0, stream>>>(feat, oi, WTbP, hWb, hWbP, colpart, ii, 1);
  k_spmm<<<256, 512, 0, stream>>>(bitsT, hWbP, hWb, ii, b1, out);

  // layer 2
  k_hw<<<256, 256, 0, stream>>>(out, oi, W2TbP, hWb, hWbP, colpart, ii, 0);
  k_spmm<<<256, 512, 0, stream>>>(bitsT, hWbP, hWb, ii, b2, out + (size_t)NN * DD);
}